// Round 11
// baseline (447.994 us; speedup 1.0000x reference)
//
#include <hip/hip_runtime.h>

typedef unsigned short u16;
typedef __bf16  bf16x8 __attribute__((ext_vector_type(8)));
typedef float   f32x4  __attribute__((ext_vector_type(4)));
typedef unsigned short us8 __attribute__((ext_vector_type(8)));
typedef _Float16 f16x8 __attribute__((ext_vector_type(8)));
typedef float   fl4   __attribute__((ext_vector_type(4)));

#define AS1 __attribute__((address_space(1)))
#define AS3 __attribute__((address_space(3)))

__device__ __forceinline__ u16 f2bf(float f) {
    union { float f; unsigned u; } x; x.f = f;
    unsigned r = x.u + 0x7fffu + ((x.u >> 16) & 1u);
    return (u16)(r >> 16);
}

// ---------------- fp32 -> bf16 cast, 6 tensors in one dispatch ----------------
__global__ __launch_bounds__(256) void cvt6(const float* __restrict__ q,
                                            const float* __restrict__ k,
                                            const float* __restrict__ v,
                                            const float* __restrict__ Wq,
                                            const float* __restrict__ Wk,
                                            const float* __restrict__ Wv,
                                            u16* __restrict__ qb, u16* __restrict__ kb,
                                            u16* __restrict__ vb, u16* __restrict__ Wqb,
                                            u16* __restrict__ Wkb, u16* __restrict__ Wvb,
                                            int n8x, int n8w) {
    const int y = blockIdx.y;
    const float* in; u16* out; int n8;
    switch (y) {
        case 0: in = q;  out = qb;  n8 = n8x; break;
        case 1: in = k;  out = kb;  n8 = n8x; break;
        case 2: in = v;  out = vb;  n8 = n8x; break;
        case 3: in = Wq; out = Wqb; n8 = n8w; break;
        case 4: in = Wk; out = Wkb; n8 = n8w; break;
        default: in = Wv; out = Wvb; n8 = n8w; break;
    }
    int i = blockIdx.x * blockDim.x + threadIdx.x;
    int stride = gridDim.x * blockDim.x;
    for (; i < n8; i += stride) {
        const fl4* p = (const fl4*)(in + (long)i * 8);
        fl4 a = p[0], b = p[1];
        us8 o;
#pragma unroll
        for (int j = 0; j < 4; ++j) { o[j] = f2bf(a[j]); o[4 + j] = f2bf(b[j]); }
        *(us8*)(out + (long)i * 8) = o;
    }
}

// ---------------- 256x256 tile bf16 GEMM, C = A * B^T ----------------
// Drain-all schedule (R8/R10 proven race-free). NEW: K-tile body split into
// 2 phases by ksub with DISJOINT fragment registers per phase. Cross-tile WAR:
// tile T+1 phase-0 ds_reads overwrite af0/bfv0, which only tile T's ks0 MFMAs
// read (drained during T's phase 1) -> T's ks1 MFMA cluster drains UNDER
// T+1's read phase; LDS and matrix pipes overlap instead of summing
// (R10 measured 5120 cyc/tile = 2050 LDS + 2480 MFMA serialized).
// MODE 0: bf16 out + bias[col]; MODE 1: bf16 out + bias[row];
// MODE 2: fp16 out * scale;     MODE 3: fp32 out.
template <int MODE>
__global__ __launch_bounds__(512, 2) void gemm256d(const u16* __restrict__ A,
                                                   const u16* __restrict__ B,
                                                   void* __restrict__ Cout,
                                                   const float* __restrict__ bias,
                                                   float scale, int K,
                                                   int lda, int ldb, int ldc,
                                                   long sAz, long sBz, long sCz) {
    __shared__ alignas(16) char lds8[2 * 65536];

    const int t    = threadIdx.x;
    const int lane = t & 63;
    const int wid  = t >> 6;
    const int wr   = wid >> 2;    // 0..1
    const int wc   = wid & 3;     // 0..3
    const int fr   = lane & 15;
    const int kq   = lane >> 4;

    const int gx  = gridDim.x;
    const int nwg = gx * gridDim.y;
    const int wg  = blockIdx.y * gx + blockIdx.x;
    const int swz = (wg & 7) * (nwg >> 3) + (wg >> 3);
    const long brow = (long)(swz / gx) * 256;
    const long bcol = (long)(swz % gx) * 256;

    const u16* Az = A + sAz * blockIdx.z;
    const u16* Bz = B + sBz * blockIdx.z;

    const int trow = t >> 3;
    const int tc8  = ((t & 7) ^ (trow & 7)) * 8;
    long offA[4], offB[4];
#pragma unroll
    for (int r = 0; r < 4; ++r) offA[r] = (brow + r * 64 + trow) * (long)lda + tc8;
#pragma unroll
    for (int r = 0; r < 4; ++r) offB[r] = (bcol + r * 64 + trow) * (long)ldb + tc8;

    int aRow[8], bRow[4], aCh[2];
#pragma unroll
    for (int m = 0; m < 8; ++m) aRow[m] = (wr * 128 + m * 16 + fr) * 128;
#pragma unroll
    for (int n = 0; n < 4; ++n) bRow[n] = 32768 + (wc * 64 + n * 16 + fr) * 128;
#pragma unroll
    for (int ks = 0; ks < 2; ++ks) aCh[ks] = (((ks << 2) | kq) ^ (fr & 7)) * 16;

    const int NT = K >> 6;
    f32x4 acc[8][4] = {};

    {
        char* bb0 = lds8;
#pragma unroll
        for (int r = 0; r < 4; ++r)
            __builtin_amdgcn_global_load_lds((const AS1 unsigned*)(Az + offA[r]),
                                             (AS3 unsigned*)(bb0 + r * 8192 + t * 16), 16, 0, 0);
#pragma unroll
        for (int r = 0; r < 4; ++r)
            __builtin_amdgcn_global_load_lds((const AS1 unsigned*)(Bz + offB[r]),
                                             (AS3 unsigned*)(bb0 + 32768 + r * 8192 + t * 16), 16, 0, 0);
    }
    __syncthreads();

    int cur = 0;
    for (int T = 0; T < NT; ++T) {
        char* bb  = lds8 + cur * 65536;
        char* bbn = lds8 + (cur ^ 1) * 65536;

        if (T + 1 < NT) {
            const long kcol = (long)(T + 1) << 6;
#pragma unroll
            for (int r = 0; r < 4; ++r)
                __builtin_amdgcn_global_load_lds((const AS1 unsigned*)(Az + offA[r] + kcol),
                                                 (AS3 unsigned*)(bbn + r * 8192 + t * 16), 16, 0, 0);
#pragma unroll
            for (int r = 0; r < 4; ++r)
                __builtin_amdgcn_global_load_lds((const AS1 unsigned*)(Bz + offB[r] + kcol),
                                                 (AS3 unsigned*)(bbn + 32768 + r * 8192 + t * 16), 16, 0, 0);
        }

        // ---- phase 0 (ks=0): 12 ds_reads into the ks0 register set, 32 MFMA.
        // Tile T-1's ks1 MFMAs drain under these reads (no reg overlap).
        bf16x8 af0[8], bf0[4], af1[8], bf1[4];
#pragma unroll
        for (int n = 0; n < 4; ++n) bf0[n] = *(const bf16x8*)(bb + bRow[n] + aCh[0]);
#pragma unroll
        for (int m = 0; m < 8; ++m) af0[m] = *(const bf16x8*)(bb + aRow[m] + aCh[0]);

#pragma unroll
        for (int m = 0; m < 8; ++m)
#pragma unroll
            for (int n = 0; n < 4; ++n)
                acc[m][n] = __builtin_amdgcn_mfma_f32_16x16x32_bf16(af0[m], bf0[n], acc[m][n], 0, 0, 0);

        // ---- phase 1 (ks=1): 12 ds_reads into the ks1 set, 32 MFMA.
        // ks0 MFMAs above drain under these reads.
#pragma unroll
        for (int n = 0; n < 4; ++n) bf1[n] = *(const bf16x8*)(bb + bRow[n] + aCh[1]);
#pragma unroll
        for (int m = 0; m < 8; ++m) af1[m] = *(const bf16x8*)(bb + aRow[m] + aCh[1]);

#pragma unroll
        for (int m = 0; m < 8; ++m)
#pragma unroll
            for (int n = 0; n < 4; ++n)
                acc[m][n] = __builtin_amdgcn_mfma_f32_16x16x32_bf16(af1[m], bf1[n], acc[m][n], 0, 0, 0);

        __syncthreads();
        cur ^= 1;
    }

    const long crow = brow + wr * 128;
    const long ccol = bcol + wc * 64;
    const long cz = sCz * blockIdx.z;
#pragma unroll
    for (int m = 0; m < 8; ++m) {
#pragma unroll
        for (int n = 0; n < 4; ++n) {
#pragma unroll
            for (int j = 0; j < 4; ++j) {
                long r = crow + m * 16 + kq * 4 + j;
                long c = ccol + n * 16 + fr;
                float vv = acc[m][n][j];
                if (MODE == 0)      { vv += bias[c]; ((u16*)Cout)[cz + r * ldc + c] = f2bf(vv); }
                else if (MODE == 1) { vv += bias[r]; ((u16*)Cout)[cz + r * ldc + c] = f2bf(vv); }
                else if (MODE == 2) { ((_Float16*)Cout)[cz + r * ldc + c] = (_Float16)(vv * scale); }
                else                { ((float*)Cout)[cz + r * ldc + c] = vv; }
            }
        }
    }
}

// ---------------- 128x128 tile bf16 GEMM (R5 proven — fallback path) ----------------
template <int MODE>
__global__ __launch_bounds__(256, 2) void gemm128(const u16* __restrict__ A,
                                                  const u16* __restrict__ B,
                                                  void* __restrict__ Cout,
                                                  const float* __restrict__ bias,
                                                  float scale, int K,
                                                  int lda, int ldb, int ldc,
                                                  long sAz, long sBz, long sCz) {
    __shared__ alignas(16) char lds8[2 * 32768];

    const int t    = threadIdx.x;
    const int lane = t & 63;
    const int wid  = t >> 6;
    const int wr   = wid >> 1;
    const int wc   = wid & 1;
    const int fr   = lane & 15;
    const int kq   = lane >> 4;

    const int gx  = gridDim.x;
    const int nwg = gx * gridDim.y;
    const int wg  = blockIdx.y * gx + blockIdx.x;
    const int swz = (wg & 7) * (nwg >> 3) + (wg >> 3);
    const long brow = (long)(swz / gx) * 128;
    const long bcol = (long)(swz % gx) * 128;

    const u16* Az = A + sAz * blockIdx.z;
    const u16* Bz = B + sBz * blockIdx.z;

    const int trow = t >> 3;
    const int tc8  = ((t & 7) ^ (trow & 7)) * 8;
    long offA[4], offB[4];
#pragma unroll
    for (int r = 0; r < 4; ++r) offA[r] = (brow + r * 32 + trow) * (long)lda + tc8;
#pragma unroll
    for (int r = 0; r < 4; ++r) offB[r] = (bcol + r * 32 + trow) * (long)ldb + tc8;

    int aRow[4], bRow[4], aCh[2];
#pragma unroll
    for (int m = 0; m < 4; ++m) aRow[m] = (wr * 64 + m * 16 + fr) * 128;
#pragma unroll
    for (int n = 0; n < 4; ++n) bRow[n] = 16384 + (wc * 64 + n * 16 + fr) * 128;
#pragma unroll
    for (int ks = 0; ks < 2; ++ks) aCh[ks] = (((ks << 2) | kq) ^ (fr & 7)) * 16;

    const int NT = K >> 6;
    f32x4 acc[4][4] = {};

    {
        char* bb0 = lds8;
#pragma unroll
        for (int r = 0; r < 4; ++r)
            __builtin_amdgcn_global_load_lds((const AS1 unsigned*)(Az + offA[r]),
                                             (AS3 unsigned*)(bb0 + r * 4096 + t * 16), 16, 0, 0);
#pragma unroll
        for (int r = 0; r < 4; ++r)
            __builtin_amdgcn_global_load_lds((const AS1 unsigned*)(Bz + offB[r]),
                                             (AS3 unsigned*)(bb0 + 16384 + r * 4096 + t * 16), 16, 0, 0);
    }
    __syncthreads();

    int cur = 0;
    for (int T = 0; T < NT; ++T) {
        char* bb  = lds8 + cur * 32768;
        char* bbn = lds8 + (cur ^ 1) * 32768;

        if (T + 1 < NT) {
            const long kcol = (long)(T + 1) << 6;
#pragma unroll
            for (int r = 0; r < 4; ++r)
                __builtin_amdgcn_global_load_lds((const AS1 unsigned*)(Az + offA[r] + kcol),
                                                 (AS3 unsigned*)(bbn + r * 4096 + t * 16), 16, 0, 0);
#pragma unroll
            for (int r = 0; r < 4; ++r)
                __builtin_amdgcn_global_load_lds((const AS1 unsigned*)(Bz + offB[r] + kcol),
                                                 (AS3 unsigned*)(bbn + 16384 + r * 4096 + t * 16), 16, 0, 0);
        }

        bf16x8 af0[4], bf0[4], af1[4], bf1[4];
#pragma unroll
        for (int m = 0; m < 4; ++m) af0[m] = *(const bf16x8*)(bb + aRow[m] + aCh[0]);
#pragma unroll
        for (int n = 0; n < 4; ++n) bf0[n] = *(const bf16x8*)(bb + bRow[n] + aCh[0]);
#pragma unroll
        for (int m = 0; m < 4; ++m)
#pragma unroll
            for (int n = 0; n < 4; ++n)
                acc[m][n] = __builtin_amdgcn_mfma_f32_16x16x32_bf16(af0[m], bf0[n], acc[m][n], 0, 0, 0);

#pragma unroll
        for (int m = 0; m < 4; ++m) af1[m] = *(const bf16x8*)(bb + aRow[m] + aCh[1]);
#pragma unroll
        for (int n = 0; n < 4; ++n) bf1[n] = *(const bf16x8*)(bb + bRow[n] + aCh[1]);
#pragma unroll
        for (int m = 0; m < 4; ++m)
#pragma unroll
            for (int n = 0; n < 4; ++n)
                acc[m][n] = __builtin_amdgcn_mfma_f32_16x16x32_bf16(af1[m], bf1[n], acc[m][n], 0, 0, 0);

        __syncthreads();
        cur ^= 1;
    }

    const long crow = brow + wr * 64;
    const long ccol = bcol + wc * 64;
    const long cz = sCz * blockIdx.z;
#pragma unroll
    for (int m = 0; m < 4; ++m) {
#pragma unroll
        for (int n = 0; n < 4; ++n) {
#pragma unroll
            for (int j = 0; j < 4; ++j) {
                long r = crow + m * 16 + kq * 4 + j;
                long c = ccol + n * 16 + fr;
                float vv = acc[m][n][j];
                if (MODE == 0)      { vv += bias[c]; ((u16*)Cout)[cz + r * ldc + c] = f2bf(vv); }
                else if (MODE == 1) { vv += bias[r]; ((u16*)Cout)[cz + r * ldc + c] = f2bf(vv); }
                else if (MODE == 2) { ((_Float16*)Cout)[cz + r * ldc + c] = (_Float16)(vv * scale); }
                else                { ((float*)Cout)[cz + r * ldc + c] = vv; }
            }
        }
    }
}

// ---------------- row softmax: fp16 in -> bf16 out, in place, L=4096 ----------------
__global__ __launch_bounds__(256) void softmax_row(u16* __restrict__ S, int L) {
    const long row = blockIdx.x;
    u16* rp = S + row * L;
    const int t = threadIdx.x;
    const int lane = t & 63, wid = t >> 6;

    f16x8 h0 = *(const f16x8*)(rp + t * 16);
    f16x8 h1 = *(const f16x8*)(rp + t * 16 + 8);
    float x[16];
#pragma unroll
    for (int j = 0; j < 8; ++j) { x[j] = (float)h0[j]; x[8 + j] = (float)h1[j]; }

    float m = -1e30f;
#pragma unroll
    for (int j = 0; j < 16; ++j) m = fmaxf(m, x[j]);
#pragma unroll
    for (int o = 32; o; o >>= 1) m = fmaxf(m, __shfl_xor(m, o));

    __shared__ float redmax[4], redsum[4];
    if (lane == 0) redmax[wid] = m;
    __syncthreads();
    m = fmaxf(fmaxf(redmax[0], redmax[1]), fmaxf(redmax[2], redmax[3]));

    float e[16], s = 0.f;
#pragma unroll
    for (int j = 0; j < 16; ++j) { e[j] = __expf(x[j] - m); s += e[j]; }
#pragma unroll
    for (int o = 32; o; o >>= 1) s += __shfl_xor(s, o);
    if (lane == 0) redsum[wid] = s;
    __syncthreads();
    s = redsum[0] + redsum[1] + redsum[2] + redsum[3];
    float inv = 1.f / s;

    us8 o0, o1;
#pragma unroll
    for (int j = 0; j < 8; ++j) { o0[j] = f2bf(e[j] * inv); o1[j] = f2bf(e[8 + j] * inv); }
    *(us8*)(rp + t * 16) = o0;
    *(us8*)(rp + t * 16 + 8) = o1;
}

extern "C" void kernel_launch(void* const* d_in, const int* in_sizes, int n_in,
                              void* d_out, int out_size, void* d_ws, size_t ws_size,
                              hipStream_t stream) {
    (void)in_sizes; (void)n_in; (void)out_size;
    const float* q  = (const float*)d_in[0];
    const float* k  = (const float*)d_in[1];
    const float* v  = (const float*)d_in[2];
    const float* Wq = (const float*)d_in[3];
    const float* bq = (const float*)d_in[4];
    const float* Wk = (const float*)d_in[5];
    const float* bk = (const float*)d_in[6];
    const float* Wv = (const float*)d_in[7];
    const float* bv = (const float*)d_in[8];
    float* out = (float*)d_out;

    constexpr long MB = 1l << 20;
    char* ws = (char*)d_ws;
    u16* pq  = (u16*)(ws + 0 * MB);     // 32 MB  [16384,1024] bf16
    u16* pk  = (u16*)(ws + 32 * MB);    // 32 MB
    u16* pvT = (u16*)(ws + 64 * MB);    // 32 MB  [1024,16384] bf16
    u16* Wqb = (u16*)(ws + 96 * MB);    // 2 MB
    u16* Wkb = (u16*)(ws + 98 * MB);    // 2 MB
    u16* Wvb = (u16*)(ws + 100 * MB);   // 2 MB
    u16* qb  = (u16*)(ws + 104 * MB);   // 32 MB (dead after projections)
    u16* kb  = (u16*)(ws + 136 * MB);   // 32 MB
    u16* vb  = (u16*)(ws + 168 * MB);   // 32 MB
    u16* S4  = (u16*)(ws + 104 * MB);   // z4: 128 MB, aliases qb/kb/vb (dead)

    const int L = 4096, E = 1024, NB = 4;
    const int n8_x = (NB * L * E) / 8;
    const int n8_w = (E * E) / 8;
    const bool z4 = ws_size >= (size_t)233 * MB;

    cvt6<<<dim3(1024, 6), 256, 0, stream>>>(q, k, v, Wq, Wk, Wv,
                                            qb, kb, vb, Wqb, Wkb, Wvb, n8_x, n8_w);

    // projections: pq = q@Wq^T + bq   (M=16384 -> gy=64, N=1024 -> gx=4) 256 blocks
    dim3 gproj(4, 64, 1);
    gemm256d<0><<<gproj, 512, 0, stream>>>(qb, Wqb, pq, bq, 1.f, E, E, E, E, 0, 0, 0);
    gemm256d<0><<<gproj, 512, 0, stream>>>(kb, Wkb, pk, bk, 1.f, E, E, E, E, 0, 0, 0);
    // pvT = Wv @ v^T + bv[row]   (M=1024 -> gy=4, N=16384 -> gx=64) 256 blocks
    dim3 gpv(64, 4, 1);
    gemm256d<1><<<gpv, 512, 0, stream>>>(Wvb, vb, pvT, bv, 1.f, E, E, E, NB * L, 0, 0, 0);

    const float scale = 0.03125f;  // 1/sqrt(1024)
    if (z4) {
        // S (fp16), all 4 batches: 1024 blocks
        gemm256d<2><<<dim3(16, 16, 4), 512, 0, stream>>>(pq, pk, S4, nullptr, scale, E, E, E, L,
                                                         (long)L * E, (long)L * E, (long)L * L);
        softmax_row<<<NB * L, 256, 0, stream>>>(S4, L);
        // PV: out = attn @ pvT^T (256 blocks)
        gemm256d<3><<<dim3(4, 16, 4), 512, 0, stream>>>(S4, pvT, out,
                                                        nullptr, 1.f, L, L, NB * L, E,
                                                        (long)L * L, (long)L, (long)L * E);
    } else {
        u16* S2 = S4;  // 64 MB, 2 batches at a time
        for (int p = 0; p < 2; ++p) {
            const long zb = p * 2;
            gemm256d<2><<<dim3(16, 16, 2), 512, 0, stream>>>(pq + zb * L * E, pk + zb * L * E,
                                                             S2, nullptr, scale, E, E, E, L,
                                                             (long)L * E, (long)L * E, (long)L * L);
            softmax_row<<<2 * L, 256, 0, stream>>>(S2, L);
            gemm256d<3><<<dim3(4, 16, 2), 512, 0, stream>>>(S2, pvT + zb * L, out + zb * L * E,
                                                            nullptr, 1.f, L, L, NB * L, E,
                                                            (long)L * L, (long)L, (long)L * E);
        }
    }
}